// Round 2
// 5709.426 us; speedup vs baseline: 1.1589x; 1.1589x over previous
//
#include <hip/hip_runtime.h>
#include <hip/hip_bf16.h>

typedef __attribute__((ext_vector_type(8))) _Float16 half8;
typedef __attribute__((ext_vector_type(4))) _Float16 half4v;
typedef __attribute__((ext_vector_type(4))) float f32x4;
typedef __attribute__((ext_vector_type(2))) float f32x2;
typedef unsigned long long u64;

#define T_SEQ 512
#define N_B   64
#define D_IN  512
#define N_U   1024

// ---- workspace layout (bytes) ----
#define OFF_H0    0ull                     /* 2 x 64x1024 fp16 (ping-pong) = 256 KiB */
#define OFF_CNT   786432ull                /* barrier flags (zeroed each launch) */
#define OFF_XB    (1ull<<20)               /* xb [512*64][512] fp16, t-major = 32 MiB */
#define OFF_WBT   (OFF_XB + 33554432ull)   /* WbT [4096][512] fp16 = 4 MiB */
#define OFF_WHT   (OFF_WBT + 4194304ull)   /* WhT [4096][1024] fp16 = 8 MiB */
#define OFF_BIAS  (OFF_WHT + 8388608ull)   /* biasv [4096] f32 */

__device__ __forceinline__ float sigf(float x) { return 1.f / (1.f + __expf(-x)); }
__device__ __forceinline__ float tanhfast(float x) { return 2.f / (1.f + __expf(-2.f * x)) - 1.f; }

// ---- pack x: xb[t*64+b][k] = fp16(x[b][t][k]) ----
__global__ __launch_bounds__(256) void pack_x(const float* __restrict__ x, _Float16* __restrict__ xb) {
  size_t i4 = ((size_t)blockIdx.x * 256 + threadIdx.x) * 4;  // grid covers 32768*512 exactly
  int m = (int)(i4 >> 9), k = (int)(i4 & 511);
  int t = m >> 6, b = m & 63;
  const float4 v = *(const float4*)(x + ((size_t)b * T_SEQ + t) * D_IN + k);
  half4v o; o.x = (_Float16)v.x; o.y = (_Float16)v.y; o.z = (_Float16)v.z; o.w = (_Float16)v.w;
  *(half4v*)(xb + i4) = o;
}

// ---- pack W: WbT[n][k] (k<512) and WhT[n][k-512], n = u*4+g (f,i,o,c) ----
__global__ __launch_bounds__(256) void pack_w(const float* __restrict__ Wf, const float* __restrict__ Wi,
                                              const float* __restrict__ Wo, const float* __restrict__ Wc,
                                              _Float16* __restrict__ WbT, _Float16* __restrict__ WhT) {
  size_t i4 = ((size_t)blockIdx.x * 256 + threadIdx.x) * 4;  // grid covers 4096*1536 exactly
  int n = (int)(i4 / 1536), k = (int)(i4 % 1536);
  int g = n & 3, u = n >> 2;
  const float* W = (g == 0) ? Wf : (g == 1) ? Wi : (g == 2) ? Wo : Wc;
  half4v o;
  o.x = (_Float16)W[(size_t)(k + 0) * N_U + u];
  o.y = (_Float16)W[(size_t)(k + 1) * N_U + u];
  o.z = (_Float16)W[(size_t)(k + 2) * N_U + u];
  o.w = (_Float16)W[(size_t)(k + 3) * N_U + u];
  if (k < D_IN) *(half4v*)(WbT + (size_t)n * D_IN + k) = o;
  else          *(half4v*)(WhT + (size_t)n * N_U + (k - D_IN)) = o;
}

__global__ __launch_bounds__(256) void pack_b(const float* __restrict__ bf_, const float* __restrict__ bi_,
                                              const float* __restrict__ bo_, const float* __restrict__ bc_,
                                              float* __restrict__ biasv) {
  int n = blockIdx.x * 256 + threadIdx.x;
  int g = n & 3, u = n >> 2;
  biasv[n] = (g == 0) ? bf_[u] : (g == 1) ? bi_[u] : (g == 2) ? bo_[u] : bc_[u];
}

// ---- persistent recurrence. 128 WGs x 256 thr; WG owns ALL 64 batches x 32 gate-cols
// (8 units). Weights (1536x32 fp16 = 96 KiB) in LDS.
// Fence-free protocol: h ping-pong moves via device-scope (sc1) RELAXED atomics —
// stores write through to the coherence point, loads read it. No buffer_wbl2 /
// buffer_inv anywhere, so L2 stays warm for xb across all 512 steps.
// Barrier: per-WG epoch flag (no atomic contention); every WG's first 128 lanes poll
// all 128 flags in parallel. Ordering: __syncthreads drains vmcnt(0) (sc1 store acked
// at coherence point == agent-visible) before the flag store.
// x-part GEMM (K=512, no h dependence) runs BEFORE the wait — hidden in the barrier
// window; only the h-part (K=1024) sits on the serial critical path.
__global__ __launch_bounds__(256, 1) void lstm_rec(
    const _Float16* __restrict__ xb, const _Float16* __restrict__ WbT,
    const _Float16* __restrict__ WhT, const float* __restrict__ biasv,
    _Float16* __restrict__ hbuf, float* __restrict__ out, unsigned* __restrict__ bar) {
  const int wg = blockIdx.x;           // 0..127
  const int tid = threadIdx.x;
  const int l = tid & 63, w = tid >> 6;
  const int col0 = wg * 32;
  const int lr = l & 15, lkb = (l >> 4) * 8;
  const int arow = w * 16 + lr;        // batch row this lane supplies

  __shared__ half8 wlds[96 * 64];      // 96 KiB: slot = kk*2+nf; kk<16 -> W_x, else W_h
  __shared__ float glds[64 * 36];      // gate tile [64 rows][32 cols], stride 36 (16B-aligned rows)

  for (int idx = tid; idx < 96 * 64; idx += 256) {
    int s = idx >> 6, l2 = idx & 63;
    int kk = s >> 1, nf = s & 1;
    int lr2 = l2 & 15, lkb2 = (l2 >> 4) * 8;
    int col = col0 + nf * 16 + lr2;
    const _Float16* src = (kk < 16)
      ? WbT + (size_t)col * D_IN + kk * 32 + lkb2
      : WhT + (size_t)col * N_U + (kk - 16) * 32 + lkb2;
    wlds[idx] = *(const half8*)src;
  }

  // elementwise mapping: 1 batch x 2 adjacent units per thread -> one packed 32b h store
  const int eb  = tid >> 2;            // batch 0..63
  const int eu2 = (tid & 3) * 2;       // local unit pair 0,2,4,6
  const int ug  = wg * 8 + eu2;        // global unit (even)
  float c0 = 0.f, c1 = 0.f;            // cell state for (eb,ug) and (eb,ug+1)
  const float bv0 = biasv[col0 + lr];
  const float bv1 = biasv[col0 + 16 + lr];

  unsigned* flags = bar;               // 128 epoch flags, zeroed at launch

  __syncthreads();

  for (int g = 0; g < T_SEQ; g++) {
    // ---- A: x-part — independent of h_g, overlaps the barrier window ----
    const _Float16* xa = xb + ((size_t)g * N_B + arow) * D_IN + lkb;
    half8 xf[16];
#pragma unroll
    for (int j = 0; j < 16; j++) xf[j] = *(const half8*)(xa + j * 32);

    f32x4 a0 = {bv0, bv0, bv0, bv0};
    f32x4 a1 = {bv1, bv1, bv1, bv1};
#pragma unroll
    for (int j = 0; j < 16; j++) {
      a0 = __builtin_amdgcn_mfma_f32_16x16x32_f16(xf[j], wlds[(j * 2 + 0) * 64 + l], a0, 0, 0, 0);
      a1 = __builtin_amdgcn_mfma_f32_16x16x32_f16(xf[j], wlds[(j * 2 + 1) * 64 + l], a1, 0, 0, 0);
    }

    // ---- B: wait until all 128 WGs have published h_g (epoch g) ----
    if (g > 0) {
      if (tid < 128) {
        while (__hip_atomic_load(&flags[tid], __ATOMIC_RELAXED, __HIP_MEMORY_SCOPE_AGENT) < (unsigned)g)
          __builtin_amdgcn_s_sleep(1);
      }
      __syncthreads();
    }

    // ---- C: h-part — sc1 loads straight from the coherence point ----
    const char* hc = (const char*)(hbuf + (size_t)(g & 1) * (N_B * N_U) + (size_t)arow * N_U + lkb);
    half8 hf[32];
#pragma unroll
    for (int j = 0; j < 32; j++) {
      u64 p0 = __hip_atomic_load((const u64*)(hc + j * 64),     __ATOMIC_RELAXED, __HIP_MEMORY_SCOPE_AGENT);
      u64 p1 = __hip_atomic_load((const u64*)(hc + j * 64 + 8), __ATOMIC_RELAXED, __HIP_MEMORY_SCOPE_AGENT);
      union { u64 u[2]; half8 v; } t; t.u[0] = p0; t.u[1] = p1;
      hf[j] = t.v;
    }
#pragma unroll
    for (int j = 0; j < 32; j++) {
      a0 = __builtin_amdgcn_mfma_f32_16x16x32_f16(hf[j], wlds[((16 + j) * 2 + 0) * 64 + l], a0, 0, 0, 0);
      a1 = __builtin_amdgcn_mfma_f32_16x16x32_f16(hf[j], wlds[((16 + j) * 2 + 1) * 64 + l], a1, 0, 0, 0);
    }

    // ---- D: gate exchange + elementwise ----
#pragma unroll
    for (int r = 0; r < 4; r++) {
      int row = w * 16 + (l >> 4) * 4 + r;
      glds[row * 36 + lr] = a0[r];
      glds[row * 36 + 16 + lr] = a1[r];
    }
    __syncthreads();

    const float* grow = &glds[eb * 36 + eu2 * 4];
    float F0 = grow[0], I0 = grow[1], O0 = grow[2], G0 = grow[3];
    float F1 = grow[4], I1 = grow[5], O1 = grow[6], G1 = grow[7];
    c0 = sigf(F0) * c0 + sigf(I0) * tanhfast(G0);
    c1 = sigf(F1) * c1 + sigf(I1) * tanhfast(G1);
    float h0v = sigf(O0) * tanhfast(c0);
    float h1v = sigf(O1) * tanhfast(c1);

    // ---- E: publish h_{g+1} — one packed sc1 store per thread ----
    unsigned hw;
    { union { _Float16 h[2]; unsigned u; } pk; pk.h[0] = (_Float16)h0v; pk.h[1] = (_Float16)h1v; hw = pk.u; }
    unsigned* hn = (unsigned*)(hbuf + (size_t)((g & 1) ^ 1) * (N_B * N_U) + (size_t)eb * N_U + ug);
    __hip_atomic_store(hn, hw, __ATOMIC_RELAXED, __HIP_MEMORY_SCOPE_AGENT);

    // ---- F: arrive — vmcnt(0) drain via __syncthreads orders h stores before flag ----
    __syncthreads();
    if (tid == 0)
      __hip_atomic_store(&flags[wg], (unsigned)(g + 1), __ATOMIC_RELAXED, __HIP_MEMORY_SCOPE_AGENT);

    // ---- G: out store, off the release path (nt: keep L2 clean for xb) ----
    f32x2 ov; ov.x = h0v; ov.y = h1v;
    __builtin_nontemporal_store(ov, (f32x2*)(out + ((size_t)eb * T_SEQ + g) * N_U + ug));
  }
}

extern "C" void kernel_launch(void* const* d_in, const int* in_sizes, int n_in,
                              void* d_out, int out_size, void* d_ws, size_t ws_size,
                              hipStream_t stream) {
  const float* x  = (const float*)d_in[0];
  const float* Wf = (const float*)d_in[1];
  const float* Wi = (const float*)d_in[2];
  const float* Wo = (const float*)d_in[3];
  const float* Wc = (const float*)d_in[4];
  const float* bf_ = (const float*)d_in[5];
  const float* bi_ = (const float*)d_in[6];
  const float* bo_ = (const float*)d_in[7];
  const float* bc_ = (const float*)d_in[8];
  float* out = (float*)d_out;

  char* ws = (char*)d_ws;
  _Float16* hbuf = (_Float16*)(ws + OFF_H0);
  unsigned* bar = (unsigned*)(ws + OFF_CNT);
  _Float16* xb   = (_Float16*)(ws + OFF_XB);
  _Float16* WbT  = (_Float16*)(ws + OFF_WBT);
  _Float16* WhT  = (_Float16*)(ws + OFF_WHT);
  float* biasv = (float*)(ws + OFF_BIAS);

  hipMemsetAsync(d_ws, 0, 1 << 20, stream);  // h ping-pong + barrier flags
  pack_x<<<16384, 256, 0, stream>>>(x, xb);
  pack_w<<<6144, 256, 0, stream>>>(Wf, Wi, Wo, Wc, WbT, WhT);
  pack_b<<<16, 256, 0, stream>>>(bf_, bi_, bo_, bc_, biasv);

  lstm_rec<<<128, 256, 0, stream>>>(xb, WbT, WhT, biasv, hbuf, out, bar);
}

// Round 3
// 3565.140 us; speedup vs baseline: 1.8560x; 1.6015x over previous
//
#include <hip/hip_runtime.h>
#include <hip/hip_bf16.h>

typedef __attribute__((ext_vector_type(8))) _Float16 half8;
typedef __attribute__((ext_vector_type(4))) _Float16 half4v;
typedef __attribute__((ext_vector_type(4))) float f32x4;
typedef __attribute__((ext_vector_type(2))) float f32x2;
typedef unsigned long long u64;

#define T_SEQ 512
#define N_B   64
#define D_IN  512
#define N_U   1024

// ---- workspace layout (bytes) ----
// hseq: one 64x1024 fp16 buffer PER TIMESTEP (513 slots, 67.25 MB). Unique address
// per step => producers sc1-write-through to MALL, readers use PLAIN cached loads
// (virgin address in every reader L2 -> first read per XCD misses to MALL, the other
// 15 WGs on that XCD hit their shared L2). No acquire fences anywhere.
#define OFF_CNT   0ull                           /* 128 epoch flags (zeroed) */
#define OFF_HSEQ  65536ull                       /* 513 x 131072 B = 67239936 */
#define OFF_XB    (OFF_HSEQ + 513ull*131072ull)  /* xb [512*64][512] fp16 = 32 MiB */
#define OFF_WBT   (OFF_XB + 33554432ull)         /* WbT [4096][512] fp16 = 4 MiB */
#define OFF_WHT   (OFF_WBT + 4194304ull)         /* WhT [4096][1024] fp16 = 8 MiB */
#define OFF_BIAS  (OFF_WHT + 8388608ull)         /* biasv [4096] f32 */

__device__ __forceinline__ float sigf(float x) { return 1.f / (1.f + __expf(-x)); }
__device__ __forceinline__ float tanhfast(float x) { return 2.f / (1.f + __expf(-2.f * x)) - 1.f; }

// ---- pack x: xb[t*64+b][k] = fp16(x[b][t][k]) ----
__global__ __launch_bounds__(256) void pack_x(const float* __restrict__ x, _Float16* __restrict__ xb) {
  size_t i4 = ((size_t)blockIdx.x * 256 + threadIdx.x) * 4;  // grid covers 32768*512 exactly
  int m = (int)(i4 >> 9), k = (int)(i4 & 511);
  int t = m >> 6, b = m & 63;
  const float4 v = *(const float4*)(x + ((size_t)b * T_SEQ + t) * D_IN + k);
  half4v o; o.x = (_Float16)v.x; o.y = (_Float16)v.y; o.z = (_Float16)v.z; o.w = (_Float16)v.w;
  *(half4v*)(xb + i4) = o;
}

// ---- pack W: WbT[n][k] (k<512) and WhT[n][k-512], n = u*4+g (f,i,o,c) ----
__global__ __launch_bounds__(256) void pack_w(const float* __restrict__ Wf, const float* __restrict__ Wi,
                                              const float* __restrict__ Wo, const float* __restrict__ Wc,
                                              _Float16* __restrict__ WbT, _Float16* __restrict__ WhT) {
  size_t i4 = ((size_t)blockIdx.x * 256 + threadIdx.x) * 4;  // grid covers 4096*1536 exactly
  int n = (int)(i4 / 1536), k = (int)(i4 % 1536);
  int g = n & 3, u = n >> 2;
  const float* W = (g == 0) ? Wf : (g == 1) ? Wi : (g == 2) ? Wo : Wc;
  half4v o;
  o.x = (_Float16)W[(size_t)(k + 0) * N_U + u];
  o.y = (_Float16)W[(size_t)(k + 1) * N_U + u];
  o.z = (_Float16)W[(size_t)(k + 2) * N_U + u];
  o.w = (_Float16)W[(size_t)(k + 3) * N_U + u];
  if (k < D_IN) *(half4v*)(WbT + (size_t)n * D_IN + k) = o;
  else          *(half4v*)(WhT + (size_t)n * N_U + (k - D_IN)) = o;
}

__global__ __launch_bounds__(256) void pack_b(const float* __restrict__ bf_, const float* __restrict__ bi_,
                                              const float* __restrict__ bo_, const float* __restrict__ bc_,
                                              float* __restrict__ biasv) {
  int n = blockIdx.x * 256 + threadIdx.x;
  int g = n & 3, u = n >> 2;
  biasv[n] = (g == 0) ? bf_[u] : (g == 1) ? bi_[u] : (g == 2) ? bo_[u] : bc_[u];
}

// ---- persistent recurrence. 128 WGs x 256 thr; WG owns ALL 64 batches x 32 gate-cols
// (8 units). Weights (1536x32 fp16 = 96 KiB) in LDS.
// Protocol (fence-free):
//   producers: packed 32b h values -> hseq[g+1] via relaxed AGENT atomic store (sc1,
//              write-through to MALL). __syncthreads drains vmcnt before flag store.
//   flag: per-WG epoch word, relaxed agent store; readers poll with 128 lanes.
//   readers: PLAIN cached loads of hseq[g] — address unique per step, so reader L2
//            can't hold a stale copy; first toucher per XCD pulls from MALL, rest hit
//            L2. Compiler-only fence after the spin (HW issue is in-order past the
//            data-dependent branch).
// x-part GEMM (K=512, no h dependence) runs BEFORE the wait; 4 independent MFMA
// accumulator chains halve dependent-MFMA latency on the critical h-part.
__global__ __launch_bounds__(256, 1) void lstm_rec(
    const _Float16* __restrict__ xb, const _Float16* __restrict__ WbT,
    const _Float16* __restrict__ WhT, const float* __restrict__ biasv,
    _Float16* __restrict__ hseq, float* __restrict__ out, unsigned* __restrict__ bar) {
  const int wg = blockIdx.x;           // 0..127
  const int tid = threadIdx.x;
  const int l = tid & 63, w = tid >> 6;
  const int col0 = wg * 32;
  const int lr = l & 15, lkb = (l >> 4) * 8;
  const int arow = w * 16 + lr;        // batch row this lane supplies

  __shared__ half8 wlds[96 * 64];      // 96 KiB: slot = kk*2+nf; kk<16 -> W_x, else W_h
  __shared__ float glds[64 * 36];      // gate tile [64 rows][32 cols], stride 36

  for (int idx = tid; idx < 96 * 64; idx += 256) {
    int s = idx >> 6, l2 = idx & 63;
    int kk = s >> 1, nf = s & 1;
    int lr2 = l2 & 15, lkb2 = (l2 >> 4) * 8;
    int col = col0 + nf * 16 + lr2;
    const _Float16* src = (kk < 16)
      ? WbT + (size_t)col * D_IN + kk * 32 + lkb2
      : WhT + (size_t)col * N_U + (kk - 16) * 32 + lkb2;
    wlds[idx] = *(const half8*)src;
  }

  // elementwise mapping: 1 batch x 2 adjacent units per thread -> one packed 32b h store
  const int eb  = tid >> 2;            // batch 0..63
  const int eu2 = (tid & 3) * 2;       // local unit pair 0,2,4,6
  const int ug  = wg * 8 + eu2;        // global unit (even)
  float c0 = 0.f, c1 = 0.f;            // cell state for (eb,ug) and (eb,ug+1)
  const float bv0 = biasv[col0 + lr];
  const float bv1 = biasv[col0 + 16 + lr];

  unsigned* flags = bar;               // 128 epoch flags, zeroed at launch

  __syncthreads();

  for (int g = 0; g < T_SEQ; g++) {
    // ---- A: x-part — independent of h_g, overlaps the barrier window ----
    const _Float16* xa = xb + ((size_t)g * N_B + arow) * D_IN + lkb;
    half8 xf[16];
#pragma unroll
    for (int j = 0; j < 16; j++) xf[j] = *(const half8*)(xa + j * 32);

    f32x4 a0 = {bv0, bv0, bv0, bv0};
    f32x4 a1 = {bv1, bv1, bv1, bv1};
    f32x4 b0 = {0.f, 0.f, 0.f, 0.f};
    f32x4 b1 = {0.f, 0.f, 0.f, 0.f};
#pragma unroll
    for (int j = 0; j < 8; j++) {
      a0 = __builtin_amdgcn_mfma_f32_16x16x32_f16(xf[j], wlds[(j * 2 + 0) * 64 + l], a0, 0, 0, 0);
      a1 = __builtin_amdgcn_mfma_f32_16x16x32_f16(xf[j], wlds[(j * 2 + 1) * 64 + l], a1, 0, 0, 0);
      b0 = __builtin_amdgcn_mfma_f32_16x16x32_f16(xf[j + 8], wlds[((j + 8) * 2 + 0) * 64 + l], b0, 0, 0, 0);
      b1 = __builtin_amdgcn_mfma_f32_16x16x32_f16(xf[j + 8], wlds[((j + 8) * 2 + 1) * 64 + l], b1, 0, 0, 0);
    }

    // ---- B: wait until all 128 WGs have published h_g (epoch g) ----
    if (g > 0) {
      if (tid < 128) {
        while (__hip_atomic_load(&flags[tid], __ATOMIC_RELAXED, __HIP_MEMORY_SCOPE_AGENT) < (unsigned)g)
          __builtin_amdgcn_s_sleep(1);
      }
      asm volatile("" ::: "memory");   // compiler fence: no hoisting of h loads
      __syncthreads();
    }

    // ---- C: h-part — PLAIN cached loads from the per-step buffer ----
    const _Float16* hp = hseq + (size_t)g * (N_B * N_U) + (size_t)arow * N_U + lkb;
    half8 hf[32];
#pragma unroll
    for (int j = 0; j < 32; j++) hf[j] = *(const half8*)(hp + j * 32);
#pragma unroll
    for (int j = 0; j < 16; j++) {
      a0 = __builtin_amdgcn_mfma_f32_16x16x32_f16(hf[j], wlds[((16 + j) * 2 + 0) * 64 + l], a0, 0, 0, 0);
      a1 = __builtin_amdgcn_mfma_f32_16x16x32_f16(hf[j], wlds[((16 + j) * 2 + 1) * 64 + l], a1, 0, 0, 0);
      b0 = __builtin_amdgcn_mfma_f32_16x16x32_f16(hf[j + 16], wlds[((32 + j) * 2 + 0) * 64 + l], b0, 0, 0, 0);
      b1 = __builtin_amdgcn_mfma_f32_16x16x32_f16(hf[j + 16], wlds[((32 + j) * 2 + 1) * 64 + l], b1, 0, 0, 0);
    }
    a0 += b0;
    a1 += b1;

    // ---- D: gate exchange + elementwise ----
#pragma unroll
    for (int r = 0; r < 4; r++) {
      int row = w * 16 + (l >> 4) * 4 + r;
      glds[row * 36 + lr] = a0[r];
      glds[row * 36 + 16 + lr] = a1[r];
    }
    __syncthreads();

    const float* grow = &glds[eb * 36 + eu2 * 4];
    float F0 = grow[0], I0 = grow[1], O0 = grow[2], G0 = grow[3];
    float F1 = grow[4], I1 = grow[5], O1 = grow[6], G1 = grow[7];
    c0 = sigf(F0) * c0 + sigf(I0) * tanhfast(G0);
    c1 = sigf(F1) * c1 + sigf(I1) * tanhfast(G1);
    float h0v = sigf(O0) * tanhfast(c0);
    float h1v = sigf(O1) * tanhfast(c1);

    // ---- E: publish h_{g+1} — one packed sc1 store per thread (write-through) ----
    unsigned hw;
    { union { _Float16 h[2]; unsigned u; } pk; pk.h[0] = (_Float16)h0v; pk.h[1] = (_Float16)h1v; hw = pk.u; }
    unsigned* hn = (unsigned*)(hseq + (size_t)(g + 1) * (N_B * N_U) + (size_t)eb * N_U + ug);
    __hip_atomic_store(hn, hw, __ATOMIC_RELAXED, __HIP_MEMORY_SCOPE_AGENT);

    // ---- F: arrive — vmcnt(0) drain via __syncthreads orders h stores before flag ----
    __syncthreads();
    if (tid == 0)
      __hip_atomic_store(&flags[wg], (unsigned)(g + 1), __ATOMIC_RELAXED, __HIP_MEMORY_SCOPE_AGENT);

    // ---- G: out store, off the release path (nt: keep L2 clean) ----
    f32x2 ov; ov.x = h0v; ov.y = h1v;
    __builtin_nontemporal_store(ov, (f32x2*)(out + ((size_t)eb * T_SEQ + g) * N_U + ug));
  }
}

extern "C" void kernel_launch(void* const* d_in, const int* in_sizes, int n_in,
                              void* d_out, int out_size, void* d_ws, size_t ws_size,
                              hipStream_t stream) {
  const float* x  = (const float*)d_in[0];
  const float* Wf = (const float*)d_in[1];
  const float* Wi = (const float*)d_in[2];
  const float* Wo = (const float*)d_in[3];
  const float* Wc = (const float*)d_in[4];
  const float* bf_ = (const float*)d_in[5];
  const float* bi_ = (const float*)d_in[6];
  const float* bo_ = (const float*)d_in[7];
  const float* bc_ = (const float*)d_in[8];
  float* out = (float*)d_out;

  char* ws = (char*)d_ws;
  unsigned* bar = (unsigned*)(ws + OFF_CNT);
  _Float16* hseq = (_Float16*)(ws + OFF_HSEQ);
  _Float16* xb   = (_Float16*)(ws + OFF_XB);
  _Float16* WbT  = (_Float16*)(ws + OFF_WBT);
  _Float16* WhT  = (_Float16*)(ws + OFF_WHT);
  float* biasv = (float*)(ws + OFF_BIAS);

  hipMemsetAsync(d_ws, 0, 1 << 20, stream);  // flags + hseq[0] (h_0 = zeros)
  pack_x<<<16384, 256, 0, stream>>>(x, xb);
  pack_w<<<6144, 256, 0, stream>>>(Wf, Wi, Wo, Wc, WbT, WhT);
  pack_b<<<16, 256, 0, stream>>>(bf_, bi_, bo_, bc_, biasv);

  lstm_rec<<<128, 256, 0, stream>>>(xb, WbT, WhT, biasv, hseq, out, bar);
}